// Round 16
// baseline (247.441 us; speedup 1.0000x reference)
//
#include <hip/hip_runtime.h>

#define IH 126
#define IW 126
#define HW 15876      // 126*126
#define OH 124
#define OW 124
#define OHW 15376     // 124*124

// Activations between kernels are HWC: a[(y*IW+x)*64 + c] (r6 win: 256 B runs).

// ---------------------------------------------------------------- conv_in (HWC out)
__global__ __launch_bounds__(256) void conv_in_kernel(
    const float* __restrict__ x, const float* __restrict__ w,
    const float* __restrict__ b, float* __restrict__ y)
{
  int tid = threadIdx.x;
  int oc = tid & 63;
  int w_ = __builtin_amdgcn_readfirstlane(tid >> 6);   // wave 0..3
  int pix = blockIdx.x * 4 + w_;
  if (pix >= HW) return;
  int h  = pix / IW;
  int wc = pix - h * IW;
  const float* wp = w + oc * 27;
  float acc = b[oc];
#pragma unroll
  for (int ci = 0; ci < 3; ci++)
#pragma unroll
    for (int ky = 0; ky < 3; ky++)
#pragma unroll
      for (int kx = 0; kx < 3; kx++)
        acc = fmaf(x[ci * 128 * 128 + (h + ky) * 128 + (wc + kx)],   // uniform
                   wp[ci * 9 + ky * 3 + kx], acc);
  y[pix * 64 + oc] = acc;
}

#define WVP4 36

// ---------------------------------------------------------------- involution v15
// All post-barrier phases LDS-PURE (no VMEM/SMEM after barrier 1):
//  - xs[140][64] LINEAR (XSW dropped: B reads global since v14, so xs is only
//    read by D at wave-uniform pos + lane=channel -> conflict-free anyway).
//  - wspan (12.5 KB) + bspan staged into LDS during phase A (coalesced
//    float4, no extra barriers) -> phase C's 25 wave-uniform s_load_dwordx16
//    chains (the last exposed scalar latency, ~20 unpipelined round-trips
//    after barrier 1) become LDS broadcasts.
//  - A: per-lane ds_write staging kept (free zero-fill at edges).
// LDS 79,952 B -> 2 blocks/CU.
__global__ __launch_bounds__(512, 4) void inv_kernel(
    const float* __restrict__ x, float* __restrict__ y,
    const float* __restrict__ wr, const float* __restrict__ br,
    const float* __restrict__ gam, const float* __restrict__ bet,
    const float* __restrict__ mu, const float* __restrict__ var,
    const float* __restrict__ wspan, const float* __restrict__ bspan)
{
  __shared__ __align__(16) float xs[140][64];    // 35,840 B (linear)
  __shared__ __align__(16) float wvs[196 * WVP4];// 28,224 B
  __shared__ __align__(16) float tss[640];       // 2,560 B; [32 px][20]
  __shared__ __align__(16) float wsm[3136];      // 12,544 B; staged span W
  __shared__ __align__(16) float wsb[196];       // 784 B;    staged span bias

  int tid = threadIdx.x;
  int bx = blockIdx.x & 15, by = blockIdx.x >> 4;
  int ox0 = bx * 8, oy0 = by * 4;
  int xh0 = ox0 - 3, yh0 = oy0 - 3;

  int w_ = __builtin_amdgcn_readfirstlane(tid >> 6);  // wave 0..7
  int ln = tid & 63;
  int p  = ln & 31;                   // pixel 0..31 (upper 32 lanes duplicate)
  int prow = p >> 3, pcol = p & 7;

  // ---- Phase A: stage x halo (14 x 10 x 64 ch, linear) + span weights/bias
  for (int idx = tid; idx < 140 * 16; idx += 512) {
    int pos = idx >> 4;
    int c4  = (idx & 15) << 2;
    int row = pos / 14;
    int col = pos - row * 14;
    int gy = yh0 + row, gx = xh0 + col;
    float4 v = make_float4(0.f, 0.f, 0.f, 0.f);
    if (gy >= 0 && gy < IH && gx >= 0 && gx < IW)
      v = *(const float4*)&x[(gy * IW + gx) * 64 + c4];
    *(float4*)&xs[pos][c4] = v;      // linear: wave writes 1KB contiguous
  }
  for (int j = tid; j < 784; j += 512)
    *(float4*)&wsm[4 * j] = *(const float4*)&wspan[4 * j];
  for (int j = tid; j < 196; j += 512) wsb[j] = bspan[j];

  // ---- Phase B (pre-barrier): t = ReLU(BN(Wr.x)) from GLOBAL x + s_load Wr
  {
    int gy = oy0 + prow; if (gy > IH - 1) gy = IH - 1;   // clamp: edge tiles
    int gx = ox0 + pcol; if (gx > IW - 1) gx = IW - 1;   // feed unstored rows
    const float* xg = &x[(gy * IW + gx) * 64];
    int cr0 = 2 * w_;
    const float* wa = wr + cr0 * 64;  // uniform -> s_load
    const float* wb = wa + 64;
    float a0 = 0.f, a1 = 0.f;
#pragma unroll
    for (int ci = 0; ci < 64; ci += 4) {
      float4 xv = *(const float4*)&xg[ci];
      a0 = fmaf(xv.x, wa[ci + 0], a0); a1 = fmaf(xv.x, wb[ci + 0], a1);
      a0 = fmaf(xv.y, wa[ci + 1], a0); a1 = fmaf(xv.y, wb[ci + 1], a1);
      a0 = fmaf(xv.z, wa[ci + 2], a0); a1 = fmaf(xv.z, wb[ci + 2], a1);
      a0 = fmaf(xv.w, wa[ci + 3], a0); a1 = fmaf(xv.w, wb[ci + 3], a1);
    }
    float s0 = gam[cr0]     * rsqrtf(var[cr0]     + 1e-5f);
    float s1 = gam[cr0 + 1] * rsqrtf(var[cr0 + 1] + 1e-5f);
    float t0 = (a0 + br[cr0]     - mu[cr0])     * s0 + bet[cr0];
    float t1 = (a1 + br[cr0 + 1] - mu[cr0 + 1]) * s1 + bet[cr0 + 1];
    if (ln < 32) {
      tss[p * 20 + cr0]     = fmaxf(t0, 0.f);
      tss[p * 20 + cr0 + 1] = fmaxf(t1, 0.f);
    }
  }
  __syncthreads();                     // xs + tss + wsm/wsb all visible

  // ---- Phase C: span — LDS-PURE (broadcast weight reads, zero VMEM/SMEM)
  {
    float tv[16];
#pragma unroll
    for (int i = 0; i < 4; i++) {
      float4 t4 = *(const float4*)&tss[p * 20 + 4 * i];
      tv[4 * i] = t4.x; tv[4 * i + 1] = t4.y;
      tv[4 * i + 2] = t4.z; tv[4 * i + 3] = t4.w;
    }
    float wv[25];
#pragma unroll
    for (int j = 0; j < 25; j++) {
      int pair = w_ + 8 * j;           // wave-uniform
      float a = 0.f;
      if (pair < 196) {
        const float* wk = &wsm[pair * 16];   // uniform LDS -> broadcast
        a = wsb[pair];
        float4 k0 = *(const float4*)&wk[0];
        float4 k1 = *(const float4*)&wk[4];
        float4 k2 = *(const float4*)&wk[8];
        float4 k3 = *(const float4*)&wk[12];
        a = fmaf(tv[0],  k0.x, a); a = fmaf(tv[1],  k0.y, a);
        a = fmaf(tv[2],  k0.z, a); a = fmaf(tv[3],  k0.w, a);
        a = fmaf(tv[4],  k1.x, a); a = fmaf(tv[5],  k1.y, a);
        a = fmaf(tv[6],  k1.z, a); a = fmaf(tv[7],  k1.w, a);
        a = fmaf(tv[8],  k2.x, a); a = fmaf(tv[9],  k2.y, a);
        a = fmaf(tv[10], k2.z, a); a = fmaf(tv[11], k2.w, a);
        a = fmaf(tv[12], k3.x, a); a = fmaf(tv[13], k3.y, a);
        a = fmaf(tv[14], k3.z, a); a = fmaf(tv[15], k3.w, a);
      }
      wv[j] = a;
    }
    if (ln < 32) {
#pragma unroll
      for (int j = 0; j < 25; j++) {
        int pair = w_ + 8 * j;
        if (pair < 196) wvs[pair * WVP4 + pcol * 4 + prow] = wv[j];
      }
    }
  }
  __syncthreads();

  // ---- Phase D: einsum — LDS-pure. wave = column w_, lane = channel.
  float acc0 = 0.f, acc1 = 0.f, acc2 = 0.f, acc3 = 0.f;
  {
    int c = ln;
    int g = ln >> 4;
    float xw[4][7];
#pragma unroll
    for (int r = 0; r < 4; r++)
#pragma unroll
      for (int kx = 0; kx < 7; kx++)
        xw[r][kx] = xs[r * 14 + w_ + kx][c];   // uniform pos + lane c: free
#pragma unroll
    for (int ky = 0; ky < 7; ky++) {
      if (ky > 0) {
#pragma unroll
        for (int r = 0; r < 3; r++)
#pragma unroll
          for (int kx = 0; kx < 7; kx++) xw[r][kx] = xw[r + 1][kx];
#pragma unroll
        for (int kx = 0; kx < 7; kx++)
          xw[3][kx] = xs[(ky + 3) * 14 + w_ + kx][c];
      }
#pragma unroll
      for (int kx = 0; kx < 7; kx++) {
        int k = ky * 7 + kx;
        float4 w4 = *(const float4*)&wvs[(g * 49 + k) * WVP4 + w_ * 4];
        acc0 = fmaf(w4.x, xw[0][kx], acc0);
        acc1 = fmaf(w4.y, xw[1][kx], acc1);
        acc2 = fmaf(w4.z, xw[2][kx], acc2);
        acc3 = fmaf(w4.w, xw[3][kx], acc3);
      }
    }
  }

  // ---- direct HWC store (outer ReLU fused)
  {
    int c = ln;
    int gx = ox0 + w_;
    if (gx < IW) {
      int base = (oy0 * IW + gx) * 64 + c;
      y[base]               = fmaxf(acc0, 0.f);
      y[base + 1 * IW * 64] = fmaxf(acc1, 0.f);
      if (oy0 + 2 < IH) y[base + 2 * IW * 64] = fmaxf(acc2, 0.f);
      if (oy0 + 3 < IH) y[base + 3 * IW * 64] = fmaxf(acc3, 0.f);
    }
  }
}

// ---------------------------------------------------------------- conv_out prep
__global__ __launch_bounds__(256) void transpose_w_kernel(
    const float* __restrict__ w, float* __restrict__ wt)
{
  int i = blockIdx.x * 256 + threadIdx.x;
  if (i >= 128 * 64 * 9) return;
  int oc = i / 576;
  int rem = i - oc * 576;
  int ci = rem / 9;
  int k = rem - ci * 9;
  wt[(k * 64 + ci) * 128 + oc] = w[i];
}

// ---------------------------------------------------------------- conv_out v3 (FROZEN)
// Best measured (42-44 us). Five alternatives (v4-v8) all regressed; do not touch.
__global__ __launch_bounds__(256, 6) void conv_out_kernel(
    const float* __restrict__ x, const float* __restrict__ wt,
    const float* __restrict__ b, float* __restrict__ y)
{
  __shared__ __align__(16) float xsm[16 * 100 * 4];   // 25,600 B
  int tid = threadIdx.x;
  int bx = blockIdx.x & 15, by = blockIdx.x >> 4;
  int oy0 = by * 8, ox0 = bx * 8;

  for (int u = tid; u < 1600; u += 256) {
    int cq = u / 100;
    int pos = u - cq * 100;
    int row = pos / 10;
    int col = pos - row * 10;
    int gy = oy0 + row, gx = ox0 + col;
    float4 v = make_float4(0.f, 0.f, 0.f, 0.f);
    if (gy < IH && gx < IW)
      v = *(const float4*)&x[(gy * IW + gx) * 64 + cq * 4];
    *(float4*)&xsm[u * 4] = v;
  }
  __syncthreads();

  int ln = tid & 63;
  int px = ln & 7, py = ln >> 3;
  int wv_ = __builtin_amdgcn_readfirstlane(tid >> 6);   // wave 0..3
  int oc8 = blockIdx.y * 32 + wv_ * 8;

  float acc[8];
#pragma unroll
  for (int j = 0; j < 8; j++) acc[j] = b[oc8 + j];

#pragma unroll
  for (int ky = 0; ky < 3; ky++) {
#pragma unroll
    for (int kx = 0; kx < 3; kx++) {
      int k = ky * 3 + kx;
      int pidx = (py + ky) * 10 + px + kx;
      const float* wp = wt + k * 64 * 128 + oc8;   // uniform -> s_loads
#pragma unroll 4
      for (int cq = 0; cq < 16; cq++) {
        float4 xv = *(const float4*)&xsm[(cq * 100 + pidx) * 4];
        const float* wq = wp + cq * 4 * 128;
#pragma unroll
        for (int j = 0; j < 8; j++) {
          acc[j] = fmaf(xv.x, wq[0 * 128 + j], acc[j]);
          acc[j] = fmaf(xv.y, wq[1 * 128 + j], acc[j]);
          acc[j] = fmaf(xv.z, wq[2 * 128 + j], acc[j]);
          acc[j] = fmaf(xv.w, wq[3 * 128 + j], acc[j]);
        }
      }
    }
  }

  int oy = oy0 + py, ox = ox0 + px;
  if (oy < OH && ox < OW) {
#pragma unroll
    for (int j = 0; j < 8; j++)
      y[(oc8 + j) * OHW + oy * OW + ox] = acc[j];
  }
}

// ---------------------------------------------------------------- launch
extern "C" void kernel_launch(void* const* d_in, const int* in_sizes, int n_in,
                              void* d_out, int out_size, void* d_ws, size_t ws_size,
                              hipStream_t stream)
{
  const float* input = (const float*)d_in[0];
  const float* ciw   = (const float*)d_in[1];
  const float* cib   = (const float*)d_in[2];
  const float* wred  = (const float*)d_in[3];
  const float* bred  = (const float*)d_in[4];
  const float* gam   = (const float*)d_in[5];
  const float* bet   = (const float*)d_in[6];
  const float* mu    = (const float*)d_in[7];
  const float* var   = (const float*)d_in[8];
  const float* wspan = (const float*)d_in[9];
  const float* bspan = (const float*)d_in[10];
  const float* cow   = (const float*)d_in[11];
  const float* cob   = (const float*)d_in[12];
  float* out = (float*)d_out;

  float* bufA = (float*)d_ws;                 // HWC: 15876*64 = 1,016,064 floats
  float* bufB = bufA + (1 << 20);             // @ 4 MiB
  float* wt   = bufA + (1 << 21);             // @ 8 MiB, 73,728 floats

  transpose_w_kernel<<<288, 256, 0, stream>>>(cow, wt);
  conv_in_kernel<<<3969, 256, 0, stream>>>(input, ciw, cib, bufA);

  float* cur = bufA; float* nxt = bufB;
  for (int i = 0; i < 6; i++) {
    inv_kernel<<<512, 512, 0, stream>>>(cur, nxt,
        wred + i * 16 * 64, bred + i * 16, gam + i * 16, bet + i * 16,
        mu + i * 16, var + i * 16, wspan + i * 196 * 16, bspan + i * 196);
    float* t = cur; cur = nxt; nxt = t;
  }
  conv_out_kernel<<<dim3(256, 4), 256, 0, stream>>>(cur, wt, cob, out);
}

// Round 17
// 231.811 us; speedup vs baseline: 1.0674x; 1.0674x over previous
//
#include <hip/hip_runtime.h>

#define IH 126
#define IW 126
#define HW 15876      // 126*126
#define OH 124
#define OW 124
#define OHW 15376     // 124*124

// Activations between kernels are HWC: a[(y*IW+x)*64 + c] (r6 win: 256 B runs).

// ---------------------------------------------------------------- conv_in (HWC out)
__global__ __launch_bounds__(256) void conv_in_kernel(
    const float* __restrict__ x, const float* __restrict__ w,
    const float* __restrict__ b, float* __restrict__ y)
{
  int tid = threadIdx.x;
  int oc = tid & 63;
  int w_ = __builtin_amdgcn_readfirstlane(tid >> 6);   // wave 0..3
  int pix = blockIdx.x * 4 + w_;
  if (pix >= HW) return;
  int h  = pix / IW;
  int wc = pix - h * IW;
  const float* wp = w + oc * 27;
  float acc = b[oc];
#pragma unroll
  for (int ci = 0; ci < 3; ci++)
#pragma unroll
    for (int ky = 0; ky < 3; ky++)
#pragma unroll
      for (int kx = 0; kx < 3; kx++)
        acc = fmaf(x[ci * 128 * 128 + (h + ky) * 128 + (wc + kx)],   // uniform
                   wp[ci * 9 + ky * 3 + kx], acc);
  y[pix * 64 + oc] = acc;
}

#define XSW(c, pos) ((c) ^ (((pos) & 7) << 3))
#define WVP4 36

// ---------------------------------------------------------------- involution v13 (BEST MEASURED, r13: 234.3us)
// v11 + phase-B half-wave split. Seven structural variants bracketed this
// design at 30.5 +/- 1 us/layer; s_load broadcast weights beat LDS staging
// (3x confirmed); do not touch without a new counter-backed mechanism.
__global__ __launch_bounds__(512, 4) void inv_kernel(
    const float* __restrict__ x, float* __restrict__ y,
    const float* __restrict__ wr, const float* __restrict__ br,
    const float* __restrict__ gam, const float* __restrict__ bet,
    const float* __restrict__ mu, const float* __restrict__ var,
    const float* __restrict__ wspan, const float* __restrict__ bspan)
{
  __shared__ __align__(16) float xs[140][68];    // 38,080 B
  __shared__ __align__(16) float wvs[196 * WVP4];// 28,224 B
  __shared__ __align__(16) float tss[640];       // 2,560 B; [32 px][20]
  __shared__ __align__(16) float wrs[1024];      // 4,096 B; staged Wr [16][64]

  int tid = threadIdx.x;
  int bx = blockIdx.x & 15, by = blockIdx.x >> 4;
  int ox0 = bx * 8, oy0 = by * 4;
  int xh0 = ox0 - 3, yh0 = oy0 - 3;

  // ---- Phase A: stage x halo (14 x 10 x 64 ch) from HWC + Wr into LDS
  for (int idx = tid; idx < 140 * 16; idx += 512) {
    int pos = idx >> 4;
    int c4  = (idx & 15) << 2;
    int row = pos / 14;
    int col = pos - row * 14;
    int gy = yh0 + row, gx = xh0 + col;
    float4 v = make_float4(0.f, 0.f, 0.f, 0.f);
    if (gy >= 0 && gy < IH && gx >= 0 && gx < IW)
      v = *(const float4*)&x[(gy * IW + gx) * 64 + c4];
    *(float4*)&xs[pos][XSW(c4, pos)] = v;
  }
  for (int j = tid; j < 1024; j += 512) wrs[j] = wr[j];
  __syncthreads();

  int w_ = __builtin_amdgcn_readfirstlane(tid >> 6);  // wave 0..7
  int ln = tid & 63;
  int p  = ln & 31;                   // pixel 0..31
  int prow = p >> 3, pcol = p & 7;
  int pc = (prow + 3) * 14 + (pcol + 3);

  // ---- Phase B: t = ReLU(BN(Wr.x)); lane = (pixel, half): cr = 2w_+(ln>>5)
  {
    int cr = 2 * w_ + (ln >> 5);
    const float* wa = &wrs[cr * 64];   // 2 addrs/wave -> broadcast, free
    float a = 0.f;
    int xsw = (pc & 7) << 3;
#pragma unroll
    for (int ci = 0; ci < 64; ci += 4) {
      int cis = ci ^ xsw;             // quad-aligned: b128-able; <=2-way banks
      float4 xv = *(const float4*)&xs[pc][cis];
      float4 av = *(const float4*)&wa[cis];
      a = fmaf(xv.x, av.x, a);
      a = fmaf(xv.y, av.y, a);
      a = fmaf(xv.z, av.z, a);
      a = fmaf(xv.w, av.w, a);
    }
    float s = gam[cr] * rsqrtf(var[cr] + 1e-5f);
    float t = (a + br[cr] - mu[cr]) * s + bet[cr];
    tss[p * 20 + cr] = fmaxf(t, 0.f);  // all 64 lanes; exact coverage
  }
  __syncthreads();

  // ---- Phase C: span. s_load weight batches; results in regs; writes deferred
  {
    float tv[16];
#pragma unroll
    for (int i = 0; i < 4; i++) {
      float4 t4 = *(const float4*)&tss[p * 20 + 4 * i];
      tv[4 * i] = t4.x; tv[4 * i + 1] = t4.y;
      tv[4 * i + 2] = t4.z; tv[4 * i + 3] = t4.w;
    }
    float wv[25];
#pragma unroll
    for (int j = 0; j < 25; j++) {
      int pair = w_ + 8 * j;           // wave-uniform
      float a = 0.f;
      if (pair < 196) {
        const float* wk = wspan + pair * 16;   // uniform -> s_load_dwordx16
        a = bspan[pair];
#pragma unroll
        for (int i = 0; i < 16; i++) a = fmaf(tv[i], wk[i], a);
      }
      wv[j] = a;
    }
    if (ln < 32) {
#pragma unroll
      for (int j = 0; j < 25; j++) {
        int pair = w_ + 8 * j;
        if (pair < 196) wvs[pair * WVP4 + pcol * 4 + prow] = wv[j];
      }
    }
  }
  __syncthreads();

  // ---- Phase D: einsum. wave = output column w_, lane = channel. (all-LDS)
  float acc0 = 0.f, acc1 = 0.f, acc2 = 0.f, acc3 = 0.f;
  {
    int c = ln;
    int g = ln >> 4;
    float xw[4][7];
#pragma unroll
    for (int r = 0; r < 4; r++)
#pragma unroll
      for (int kx = 0; kx < 7; kx++) {
        int pos = r * 14 + w_ + kx;
        xw[r][kx] = xs[pos][XSW(c, pos)];
      }
#pragma unroll
    for (int ky = 0; ky < 7; ky++) {
      if (ky > 0) {
#pragma unroll
        for (int r = 0; r < 3; r++)
#pragma unroll
          for (int kx = 0; kx < 7; kx++) xw[r][kx] = xw[r + 1][kx];
#pragma unroll
        for (int kx = 0; kx < 7; kx++) {
          int pos = (ky + 3) * 14 + w_ + kx;
          xw[3][kx] = xs[pos][XSW(c, pos)];
        }
      }
#pragma unroll
      for (int kx = 0; kx < 7; kx++) {
        int k = ky * 7 + kx;
        float4 w4 = *(const float4*)&wvs[(g * 49 + k) * WVP4 + w_ * 4];
        acc0 = fmaf(w4.x, xw[0][kx], acc0);
        acc1 = fmaf(w4.y, xw[1][kx], acc1);
        acc2 = fmaf(w4.z, xw[2][kx], acc2);
        acc3 = fmaf(w4.w, xw[3][kx], acc3);
      }
    }
  }

  // ---- direct HWC store (outer ReLU fused)
  {
    int c = ln;
    int gx = ox0 + w_;
    if (gx < IW) {
      int base = (oy0 * IW + gx) * 64 + c;
      y[base]               = fmaxf(acc0, 0.f);
      y[base + 1 * IW * 64] = fmaxf(acc1, 0.f);
      if (oy0 + 2 < IH) y[base + 2 * IW * 64] = fmaxf(acc2, 0.f);
      if (oy0 + 3 < IH) y[base + 3 * IW * 64] = fmaxf(acc3, 0.f);
    }
  }
}

// ---------------------------------------------------------------- conv_out prep
__global__ __launch_bounds__(256) void transpose_w_kernel(
    const float* __restrict__ w, float* __restrict__ wt)
{
  int i = blockIdx.x * 256 + threadIdx.x;
  if (i >= 128 * 64 * 9) return;
  int oc = i / 576;
  int rem = i - oc * 576;
  int ci = rem / 9;
  int k = rem - ci * 9;
  wt[(k * 64 + ci) * 128 + oc] = w[i];
}

// ---------------------------------------------------------------- conv_out v3 (FROZEN)
// Best measured (42-44 us). Five alternatives (v4-v8) all regressed; do not touch.
__global__ __launch_bounds__(256, 6) void conv_out_kernel(
    const float* __restrict__ x, const float* __restrict__ wt,
    const float* __restrict__ b, float* __restrict__ y)
{
  __shared__ __align__(16) float xsm[16 * 100 * 4];   // 25,600 B
  int tid = threadIdx.x;
  int bx = blockIdx.x & 15, by = blockIdx.x >> 4;
  int oy0 = by * 8, ox0 = bx * 8;

  for (int u = tid; u < 1600; u += 256) {
    int cq = u / 100;
    int pos = u - cq * 100;
    int row = pos / 10;
    int col = pos - row * 10;
    int gy = oy0 + row, gx = ox0 + col;
    float4 v = make_float4(0.f, 0.f, 0.f, 0.f);
    if (gy < IH && gx < IW)
      v = *(const float4*)&x[(gy * IW + gx) * 64 + cq * 4];
    *(float4*)&xsm[u * 4] = v;
  }
  __syncthreads();

  int ln = tid & 63;
  int px = ln & 7, py = ln >> 3;
  int wv_ = __builtin_amdgcn_readfirstlane(tid >> 6);   // wave 0..3
  int oc8 = blockIdx.y * 32 + wv_ * 8;

  float acc[8];
#pragma unroll
  for (int j = 0; j < 8; j++) acc[j] = b[oc8 + j];

#pragma unroll
  for (int ky = 0; ky < 3; ky++) {
#pragma unroll
    for (int kx = 0; kx < 3; kx++) {
      int k = ky * 3 + kx;
      int pidx = (py + ky) * 10 + px + kx;
      const float* wp = wt + k * 64 * 128 + oc8;   // uniform -> s_loads
#pragma unroll 4
      for (int cq = 0; cq < 16; cq++) {
        float4 xv = *(const float4*)&xsm[(cq * 100 + pidx) * 4];
        const float* wq = wp + cq * 4 * 128;
#pragma unroll
        for (int j = 0; j < 8; j++) {
          acc[j] = fmaf(xv.x, wq[0 * 128 + j], acc[j]);
          acc[j] = fmaf(xv.y, wq[1 * 128 + j], acc[j]);
          acc[j] = fmaf(xv.z, wq[2 * 128 + j], acc[j]);
          acc[j] = fmaf(xv.w, wq[3 * 128 + j], acc[j]);
        }
      }
    }
  }

  int oy = oy0 + py, ox = ox0 + px;
  if (oy < OH && ox < OW) {
#pragma unroll
    for (int j = 0; j < 8; j++)
      y[(oc8 + j) * OHW + oy * OW + ox] = acc[j];
  }
}

// ---------------------------------------------------------------- launch
extern "C" void kernel_launch(void* const* d_in, const int* in_sizes, int n_in,
                              void* d_out, int out_size, void* d_ws, size_t ws_size,
                              hipStream_t stream)
{
  const float* input = (const float*)d_in[0];
  const float* ciw   = (const float*)d_in[1];
  const float* cib   = (const float*)d_in[2];
  const float* wred  = (const float*)d_in[3];
  const float* bred  = (const float*)d_in[4];
  const float* gam   = (const float*)d_in[5];
  const float* bet   = (const float*)d_in[6];
  const float* mu    = (const float*)d_in[7];
  const float* var   = (const float*)d_in[8];
  const float* wspan = (const float*)d_in[9];
  const float* bspan = (const float*)d_in[10];
  const float* cow   = (const float*)d_in[11];
  const float* cob   = (const float*)d_in[12];
  float* out = (float*)d_out;

  float* bufA = (float*)d_ws;                 // HWC: 15876*64 = 1,016,064 floats
  float* bufB = bufA + (1 << 20);             // @ 4 MiB
  float* wt   = bufA + (1 << 21);             // @ 8 MiB, 73,728 floats

  transpose_w_kernel<<<288, 256, 0, stream>>>(cow, wt);
  conv_in_kernel<<<3969, 256, 0, stream>>>(input, ciw, cib, bufA);

  float* cur = bufA; float* nxt = bufB;
  for (int i = 0; i < 6; i++) {
    inv_kernel<<<512, 512, 0, stream>>>(cur, nxt,
        wred + i * 16 * 64, bred + i * 16, gam + i * 16, bet + i * 16,
        mu + i * 16, var + i * 16, wspan + i * 196 * 16, bspan + i * 196);
    float* t = cur; cur = nxt; nxt = t;
  }
  conv_out_kernel<<<dim3(256, 4), 256, 0, stream>>>(cur, wt, cob, out);
}